// Round 1
// 1060.177 us; speedup vs baseline: 1.0762x; 1.0762x over previous
//
#include <hip/hip_runtime.h>

#define B_    4
#define T_    256
#define U_    128
#define ENC_H 512
#define PRED_H 640
#define JH    640
#define V_    1025
#define VMAIN 1024

#define BM    64
#define KC    32
#define NKC   (JH / KC)   // 20
#define PA    648         // LDS A pitch in bf16 elems: 640 + 8 -> stride 324 dwords = 4 mod 32 (2-way free)

typedef float f32x4  __attribute__((ext_vector_type(4)));
typedef short bf16x8 __attribute__((ext_vector_type(8)));

__device__ __forceinline__ short bf16_rne(float x) {
    unsigned u = __float_as_uint(x);
    unsigned r = (u + 0x7fffu + ((u >> 16) & 1u)) >> 16;
    return (short)r;
}

// ---------------------------------------------------------------------------
// fp32 projection GEMM: Y[(b*M+m)][n] = sum_k X[b][k][m] * W[n][k] + bias[n]
// grid: (M/64, N/64, B), block 256. 64x64 tile, 4x4 per thread, float4 LDS reads.
// ---------------------------------------------------------------------------
__global__ __launch_bounds__(256) void proj_kernel(
    const float* __restrict__ X, const float* __restrict__ W,
    const float* __restrict__ bias, float* __restrict__ Y,
    int K, int M, int N)
{
    __shared__ float Xs[16][68];
    __shared__ float Wt[16][68];

    const int b  = blockIdx.z;
    const int m0 = blockIdx.x * 64;
    const int n0 = blockIdx.y * 64;
    const int tid = threadIdx.x;
    const int tm = tid & 15;       // m quad
    const int tn = tid >> 4;       // n quad

    const float* Xb = X + (size_t)b * K * M;

    // staging maps
    const int lk = tid >> 4;          // X: k row 0..15
    const int lm = (tid & 15) * 4;    // X: m offset (float4)
    const int wn = tid >> 2;          // W: n row 0..63
    const int wk = (tid & 3) * 4;     // W: k offset (float4), coalesced 64B/row

    float acc[4][4];
    #pragma unroll
    for (int i = 0; i < 4; ++i)
        #pragma unroll
        for (int j = 0; j < 4; ++j) acc[i][j] = 0.f;

    for (int k0 = 0; k0 < K; k0 += 16) {
        float4 xv = *(const float4*)(Xb + (size_t)(k0 + lk) * M + m0 + lm);
        *(float4*)&Xs[lk][lm] = xv;
        float4 wv4 = *(const float4*)(W + (size_t)(n0 + wn) * K + k0 + wk);
        Wt[wk + 0][wn] = wv4.x;
        Wt[wk + 1][wn] = wv4.y;
        Wt[wk + 2][wn] = wv4.z;
        Wt[wk + 3][wn] = wv4.w;
        __syncthreads();
        #pragma unroll
        for (int k = 0; k < 16; ++k) {
            float4 a4 = *(const float4*)&Xs[k][tm * 4];
            float4 b4 = *(const float4*)&Wt[k][tn * 4];
            acc[0][0] += a4.x * b4.x; acc[0][1] += a4.x * b4.y;
            acc[0][2] += a4.x * b4.z; acc[0][3] += a4.x * b4.w;
            acc[1][0] += a4.y * b4.x; acc[1][1] += a4.y * b4.y;
            acc[1][2] += a4.y * b4.z; acc[1][3] += a4.y * b4.w;
            acc[2][0] += a4.z * b4.x; acc[2][1] += a4.z * b4.y;
            acc[2][2] += a4.z * b4.z; acc[2][3] += a4.z * b4.w;
            acc[3][0] += a4.w * b4.x; acc[3][1] += a4.w * b4.y;
            acc[3][2] += a4.w * b4.z; acc[3][3] += a4.w * b4.w;
        }
        __syncthreads();
    }

    float4 bv = *(const float4*)(bias + n0 + tn * 4);
    #pragma unroll
    for (int i = 0; i < 4; ++i) {
        const int m = m0 + tm * 4 + i;
        float4 o;
        o.x = acc[i][0] + bv.x;
        o.y = acc[i][1] + bv.y;
        o.z = acc[i][2] + bv.z;
        o.w = acc[i][3] + bv.w;
        *(float4*)(Y + (size_t)(b * M + m) * N + n0 + tn * 4) = o;
    }
}

// ---------------------------------------------------------------------------
// fp32 -> bf16 convert (W_joint rows 0..1023), x4 vectorized
// ---------------------------------------------------------------------------
__global__ __launch_bounds__(256) void cvt_kernel(
    const float* __restrict__ W, short* __restrict__ o, int n)
{
    int i = (blockIdx.x * 256 + threadIdx.x) * 4;
    if (i < n) {
        float4 v = *(const float4*)(W + i);
        short4 s;
        s.x = bf16_rne(v.x);
        s.y = bf16_rne(v.y);
        s.z = bf16_rne(v.z);
        s.w = bf16_rne(v.w);
        *(short4*)(o + i) = s;
    }
}

// ---------------------------------------------------------------------------
// Fused joint GEMM + log_softmax, barrier-free main loop.
// grid.x = B*T*2 (each WG: one (b,t), 64 u-rows). block = 1024 (16 waves).
// Full hidden A tile (64 x 640 bf16) staged ONCE in LDS, one barrier, then
// 20 unrolled K-chunks of pure {ds_read_b128 + global dwordx4 + MFMA} with
// no syncs — waves free-run at 4/SIMD.
// ---------------------------------------------------------------------------
__global__ __launch_bounds__(1024) void joint_kernel(
    const float* __restrict__ f,       // [B*T][640]
    const float* __restrict__ g,       // [B*U][640]
    const short* __restrict__ wj,      // [1024][640] bf16
    const float* __restrict__ Wj32,    // [1025][640] fp32 (row 1024 used)
    const float* __restrict__ bj,      // [1025]
    float* __restrict__ out)           // [B*T*U][1025]
{
    __shared__ __align__(16) short As[BM * PA];          // 82,944 B
    __shared__ float red[BM][16];                        // 4 KB
    __shared__ float zp[BM][16];                         // 4 KB
    __shared__ float rowmax_s[BM], lse_s[BM], z1024_s[BM];

    const int bt = blockIdx.x >> 1;
    const int uh = blockIdx.x & 1;
    const int b  = bt >> 8;             // T=256
    const int u0 = uh * BM;

    const float* frow = f + (size_t)bt * JH;
    const float* grow = g + (size_t)(b * U_ + u0) * JH;

    const int tid  = threadIdx.x;
    const int lane = tid & 63;
    const int wv   = tid >> 6;          // 0..15 col group
    const int q    = lane >> 4;         // quad
    const int l15  = lane & 15;

    // ---- stage full hidden tile (64 rows x 640 k) as bf16, vectorized ----
    {
        const int su = tid >> 4;        // row 0..63
        const int sp = tid & 15;        // k part
        const float* gr = grow + (size_t)su * JH;
        short* dst = As + su * PA;
        #pragma unroll
        for (int i = 0; i < 10; ++i) {
            const int k = sp * 4 + i * 64;   // lanes cover 256B contiguous per i
            float4 fv = *(const float4*)(frow + k);
            float4 gv = *(const float4*)(gr + k);
            short4 h;
            h.x = bf16_rne(fmaxf(fv.x + gv.x, 0.f));
            h.y = bf16_rne(fmaxf(fv.y + gv.y, 0.f));
            h.z = bf16_rne(fmaxf(fv.z + gv.z, 0.f));
            h.w = bf16_rne(fmaxf(fv.w + gv.w, 0.f));
            *(short4*)(dst + k) = h;
        }
    }
    __syncthreads();

    // ---- barrier-free MFMA loop ----
    f32x4 acc[4][4];
    #pragma unroll
    for (int rt = 0; rt < 4; ++rt)
        #pragma unroll
        for (int ct = 0; ct < 4; ++ct)
            acc[rt][ct] = (f32x4){0.f, 0.f, 0.f, 0.f};

    const short* bptr[4];
    #pragma unroll
    for (int ct = 0; ct < 4; ++ct)
        bptr[ct] = wj + (size_t)((wv << 6) + (ct << 4) + l15) * JH + (q << 3);
    const short* aptr[4];
    #pragma unroll
    for (int rt = 0; rt < 4; ++rt)
        aptr[rt] = As + (rt * 16 + l15) * PA + (q << 3);

    #pragma unroll
    for (int kc = 0; kc < NKC; ++kc) {
        bf16x8 bfr[4], afr[4];
        #pragma unroll
        for (int ct = 0; ct < 4; ++ct)
            bfr[ct] = *(const bf16x8*)(bptr[ct] + kc * KC);
        #pragma unroll
        for (int rt = 0; rt < 4; ++rt)
            afr[rt] = *(const bf16x8*)(aptr[rt] + kc * KC);
        #pragma unroll
        for (int rt = 0; rt < 4; ++rt)
            #pragma unroll
            for (int ct = 0; ct < 4; ++ct)
                acc[rt][ct] = __builtin_amdgcn_mfma_f32_16x16x32_bf16(
                    afr[rt], bfr[ct], acc[rt][ct], 0, 0, 0);
    }

    // ---- epilogue: bias + fused log_softmax (unchanged, proven) ----
    float mloc[4][4];
    #pragma unroll
    for (int rt = 0; rt < 4; ++rt)
        #pragma unroll
        for (int r = 0; r < 4; ++r) mloc[rt][r] = -3.0e38f;

    #pragma unroll
    for (int ct = 0; ct < 4; ++ct) {
        const float bb = bj[(wv << 6) + (ct << 4) + l15];
        #pragma unroll
        for (int rt = 0; rt < 4; ++rt)
            #pragma unroll
            for (int r = 0; r < 4; ++r) {
                acc[rt][ct][r] += bb;
                mloc[rt][r] = fmaxf(mloc[rt][r], acc[rt][ct][r]);
            }
    }
    #pragma unroll
    for (int off = 1; off < 16; off <<= 1)
        #pragma unroll
        for (int rt = 0; rt < 4; ++rt)
            #pragma unroll
            for (int r = 0; r < 4; ++r)
                mloc[rt][r] = fmaxf(mloc[rt][r], __shfl_xor(mloc[rt][r], off));
    if (l15 == 0) {
        #pragma unroll
        for (int rt = 0; rt < 4; ++rt)
            #pragma unroll
            for (int r = 0; r < 4; ++r)
                red[rt * 16 + (q << 2) + r][wv] = mloc[rt][r];
    }
    // class-1024 logit, fp32 (16 threads per row, 40 k each, float4)
    {
        const int row  = tid >> 4;
        const int part = tid & 15;
        const float* w1024 = Wj32 + (size_t)VMAIN * JH;
        const float* gr = grow + (size_t)row * JH;
        const int kb = part * 40;
        float s = 0.f;
        #pragma unroll
        for (int i = 0; i < 10; ++i) {
            float4 fv = *(const float4*)(frow + kb + i * 4);
            float4 gv = *(const float4*)(gr + kb + i * 4);
            float4 wv4 = *(const float4*)(w1024 + kb + i * 4);
            s += fmaxf(fv.x + gv.x, 0.f) * wv4.x
               + fmaxf(fv.y + gv.y, 0.f) * wv4.y
               + fmaxf(fv.z + gv.z, 0.f) * wv4.z
               + fmaxf(fv.w + gv.w, 0.f) * wv4.w;
        }
        zp[row][part] = s;
    }
    __syncthreads();

    if (tid < BM) {
        float mx = red[tid][0];
        #pragma unroll
        for (int w = 1; w < 16; ++w) mx = fmaxf(mx, red[tid][w]);
        float z = bj[VMAIN];
        #pragma unroll
        for (int w = 0; w < 16; ++w) z += zp[tid][w];
        mx = fmaxf(mx, z);
        rowmax_s[tid] = mx;
        z1024_s[tid]  = z;
    }
    __syncthreads();

    float sloc[4][4];
    #pragma unroll
    for (int rt = 0; rt < 4; ++rt)
        #pragma unroll
        for (int r = 0; r < 4; ++r) {
            const float mx = rowmax_s[rt * 16 + (q << 2) + r];
            float s = 0.f;
            #pragma unroll
            for (int ct = 0; ct < 4; ++ct)
                s += __expf(acc[rt][ct][r] - mx);
            sloc[rt][r] = s;
        }
    #pragma unroll
    for (int off = 1; off < 16; off <<= 1)
        #pragma unroll
        for (int rt = 0; rt < 4; ++rt)
            #pragma unroll
            for (int r = 0; r < 4; ++r)
                sloc[rt][r] += __shfl_xor(sloc[rt][r], off);
    if (l15 == 0) {
        #pragma unroll
        for (int rt = 0; rt < 4; ++rt)
            #pragma unroll
            for (int r = 0; r < 4; ++r)
                red[rt * 16 + (q << 2) + r][wv] = sloc[rt][r];
    }
    __syncthreads();

    const size_t obase = (size_t)(bt * U_ + u0) * V_;
    if (tid < BM) {
        float tot = __expf(z1024_s[tid] - rowmax_s[tid]);
        #pragma unroll
        for (int w = 0; w < 16; ++w) tot += red[tid][w];
        float lse = rowmax_s[tid] + __logf(tot);
        lse_s[tid] = lse;
        out[obase + (size_t)tid * V_ + VMAIN] = z1024_s[tid] - lse;
    }
    __syncthreads();

    #pragma unroll
    for (int rt = 0; rt < 4; ++rt)
        #pragma unroll
        for (int r = 0; r < 4; ++r) {
            const int row = rt * 16 + (q << 2) + r;
            const float l = lse_s[row];
            #pragma unroll
            for (int ct = 0; ct < 4; ++ct) {
                const int col = (wv << 6) + (ct << 4) + l15;
                out[obase + (size_t)row * V_ + col] = acc[rt][ct][r] - l;
            }
        }
}

// ---------------------------------------------------------------------------
extern "C" void kernel_launch(void* const* d_in, const int* in_sizes, int n_in,
                              void* d_out, int out_size, void* d_ws, size_t ws_size,
                              hipStream_t stream) {
    const float* enc   = (const float*)d_in[0];
    const float* dec   = (const float*)d_in[1];
    const float* Wenc  = (const float*)d_in[2];
    const float* benc  = (const float*)d_in[3];
    const float* Wpred = (const float*)d_in[4];
    const float* bpred = (const float*)d_in[5];
    const float* Wj    = (const float*)d_in[6];
    const float* bjt   = (const float*)d_in[7];
    float* out = (float*)d_out;

    char* ws = (char*)d_ws;
    float* f_ws  = (float*)ws;                              // 1024*640 f32 = 2.62 MB
    float* g_ws  = (float*)(ws + 2621440);                  // 512*640 f32 = 1.31 MB
    short* wj_ws = (short*)(ws + 2621440 + 1310720);        // 1024*640 bf16 = 1.31 MB

    proj_kernel<<<dim3(4, 10, 4), 256, 0, stream>>>(enc, Wenc, benc, f_ws, ENC_H, T_, JH);
    proj_kernel<<<dim3(2, 10, 4), 256, 0, stream>>>(dec, Wpred, bpred, g_ws, PRED_H, JH == JH ? U_ : U_, JH);
    cvt_kernel<<<dim3((VMAIN * JH / 4 + 255) / 256), 256, 0, stream>>>(Wj, wj_ws, VMAIN * JH);
    joint_kernel<<<dim3(B_ * T_ * 2), 1024, 0, stream>>>(f_ws, g_ws, wj_ws, Wj, bjt, out);
}